// Round 1
// baseline (554.655 us; speedup 1.0000x reference)
//
#include <hip/hip_runtime.h>
#include <math.h>

#define BB 4
#define SS 8192
#define HH 16
#define DD 64
#define ROT 32
#define NG (BB * SS * HH)  // 524288 token-heads

// ---------------------------------------------------------------------------
// Kernel 1: build M = G_comb @ matrix  (64x64 fp32), one block of 64 threads.
// G_comb = I @ G_0 @ ... @ G_31 ; acc@G is a column-op touching cols i,j only,
// and each row is independent -> thread t owns row t in LDS, no syncs needed.
// Edge case i==j: the JAX .at[].set() chain ends with G[i,i]=sin -> col *= sn.
// ---------------------------------------------------------------------------
__global__ void setup_M(const float* __restrict__ matrix,
                        const float* __restrict__ thetas,
                        const float* __restrict__ tscale,
                        const int* __restrict__ pairs,
                        float* __restrict__ M) {
  __shared__ float G[DD][DD];
  const int t = threadIdx.x;  // 0..63, owns row t
  for (int c = 0; c < DD; ++c) G[t][c] = (t == c) ? 1.0f : 0.0f;
  const float ts = tscale[0];
  for (int r = 0; r < ROT; ++r) {
    const int i = pairs[2 * r + 0];
    const int j = pairs[2 * r + 1];
    const float th = thetas[r] * ts;
    const float cc = cosf(th);
    const float sn = sinf(th);
    if (i == j) {
      G[t][i] *= sn;
    } else {
      const float a = G[t][i];
      const float b = G[t][j];
      G[t][i] = a * cc + b * sn;
      G[t][j] = b * cc - a * sn;
    }
  }
  // M[t][c] = sum_k G[t][k] * matrix[k][c]   (reads own row only)
  for (int c = 0; c < DD; ++c) {
    float s = 0.0f;
    for (int k = 0; k < DD; ++k) s = fmaf(G[t][k], matrix[k * DD + c], s);
    M[t * DD + c] = s;
  }
}

// ---------------------------------------------------------------------------
// Kernel 2: cos/sin table. sc[s*64 + d] = cos(s*invf[d]), sc[s*64+32+d] = sin.
// 2 MB total; L2/L3-resident during the main kernel.
// ---------------------------------------------------------------------------
__global__ void setup_table(const float* __restrict__ invf,
                            float* __restrict__ sc) {
  const int idx = blockIdx.x * blockDim.x + threadIdx.x;
  if (idx >= SS * 32) return;
  const int s = idx >> 5;
  const int d = idx & 31;
  const float ang = (float)s * invf[d];
  sc[s * 64 + d] = cosf(ang);
  sc[s * 64 + 32 + d] = sinf(ang);
}

// ---------------------------------------------------------------------------
// Kernel 3: one thread per token-head. 64 fp32 accumulators; M is read with
// wave-uniform addresses (expect s_load -> SGPR operands for the FMAs).
// Epilogue: out[d] = (a2d*cos - a2d1*sin)*32 ; out[32+d] = (a2d*sin + a2d1*cos)*32
// ---------------------------------------------------------------------------
__global__ __launch_bounds__(256) void apply_rot(const float* __restrict__ x,
                                                 const float* __restrict__ M,
                                                 const float* __restrict__ sc,
                                                 const float* __restrict__ invf,
                                                 float* __restrict__ out) {
  const int g = blockIdx.x * 256 + threadIdx.x;  // token-head id, grid is exact
  const float4* __restrict__ xv = (const float4*)(x + (size_t)g * DD);

  float acc[DD];
#pragma unroll
  for (int c = 0; c < DD; ++c) acc[c] = 0.0f;

  float4 xq = xv[0];
  for (int k4 = 0; k4 < 16; ++k4) {
    const float4 xn = (k4 < 15) ? xv[k4 + 1] : xq;  // prefetch next
    const float* __restrict__ Mr = M + k4 * 4 * DD; // uniform address
#pragma unroll
    for (int c = 0; c < DD; ++c) acc[c] = fmaf(xq.x, Mr[c], acc[c]);
#pragma unroll
    for (int c = 0; c < DD; ++c) acc[c] = fmaf(xq.y, Mr[DD + c], acc[c]);
#pragma unroll
    for (int c = 0; c < DD; ++c) acc[c] = fmaf(xq.z, Mr[2 * DD + c], acc[c]);
#pragma unroll
    for (int c = 0; c < DD; ++c) acc[c] = fmaf(xq.w, Mr[3 * DD + c], acc[c]);
    xq = xn;
  }

  const int s = (g >> 4) & (SS - 1);  // g = ((b*S + s)*H + h)
  const float4* __restrict__ scv = (const float4*)(sc + (size_t)s * 64);
  float4* __restrict__ ov = (float4*)(out + (size_t)g * DD);

#pragma unroll
  for (int q = 0; q < 8; ++q) {
    float4 cv, sv;
    if (sc) {
      cv = scv[q];
      sv = scv[8 + q];
    } else {  // fallback: compute inline (only if ws too small for table)
      const float a0 = (float)s * invf[4 * q + 0];
      const float a1 = (float)s * invf[4 * q + 1];
      const float a2 = (float)s * invf[4 * q + 2];
      const float a3 = (float)s * invf[4 * q + 3];
      cv = make_float4(cosf(a0), cosf(a1), cosf(a2), cosf(a3));
      sv = make_float4(sinf(a0), sinf(a1), sinf(a2), sinf(a3));
    }
    const float e0 = acc[8 * q + 0], o0 = acc[8 * q + 1];
    const float e1 = acc[8 * q + 2], o1 = acc[8 * q + 3];
    const float e2 = acc[8 * q + 4], o2 = acc[8 * q + 5];
    const float e3 = acc[8 * q + 6], o3 = acc[8 * q + 7];
    float4 lo, hi;
    lo.x = (e0 * cv.x - o0 * sv.x) * 32.0f;
    hi.x = (e0 * sv.x + o0 * cv.x) * 32.0f;
    lo.y = (e1 * cv.y - o1 * sv.y) * 32.0f;
    hi.y = (e1 * sv.y + o1 * cv.y) * 32.0f;
    lo.z = (e2 * cv.z - o2 * sv.z) * 32.0f;
    hi.z = (e2 * sv.z + o2 * cv.z) * 32.0f;
    lo.w = (e3 * cv.w - o3 * sv.w) * 32.0f;
    hi.w = (e3 * sv.w + o3 * cv.w) * 32.0f;
    ov[q] = lo;
    ov[8 + q] = hi;
  }
}

// ---------------------------------------------------------------------------
extern "C" void kernel_launch(void* const* d_in, const int* in_sizes, int n_in,
                              void* d_out, int out_size, void* d_ws,
                              size_t ws_size, hipStream_t stream) {
  const float* x = (const float*)d_in[0];       // (4, 8192, 1024) f32
  const float* matrix = (const float*)d_in[1];  // (64, 64) f32
  const float* thetas = (const float*)d_in[2];  // (32,) f32
  const float* tscale = (const float*)d_in[3];  // (1,) f32
  const float* invf = (const float*)d_in[4];    // (32,) f32
  const int* pairs = (const int*)d_in[5];       // (32, 2) i32
  float* out = (float*)d_out;

  float* M = (float*)d_ws;  // 64*64 fp32 = 16 KB
  float* sc = nullptr;      // 8192*64 fp32 = 2 MB table (optional)
  const size_t need = (size_t)DD * DD * sizeof(float) +
                      (size_t)SS * 64 * sizeof(float);
  if (ws_size >= need) sc = (float*)d_ws + DD * DD;

  setup_M<<<1, 64, 0, stream>>>(matrix, thetas, tscale, pairs, M);
  if (sc) {
    setup_table<<<(SS * 32 + 255) / 256, 256, 0, stream>>>(invf, sc);
  }
  apply_rot<<<NG / 256, 256, 0, stream>>>(x, M, sc, invf, out);
}

// Round 2
// 285.574 us; speedup vs baseline: 1.9422x; 1.9422x over previous
//
#include <hip/hip_runtime.h>
#include <math.h>

#define BB 4
#define SS 8192
#define HH 16
#define DD 64
#define ROT 32
#define NG (BB * SS * HH)  // 524288 token-head rows
#define RPB 128            // rows per block
#define LSTR 65            // LDS row stride in floats (pad +1 -> rotated banks)

// ---------------------------------------------------------------------------
// G_comb = I @ G_0 @ ... @ G_31. acc@G is a column-op; thread t owns row t,
// touches only its own row -> no syncs. i==j edge: .at chain leaves G[i,i]=sin.
// ---------------------------------------------------------------------------
__global__ void setup_G(const float* __restrict__ thetas,
                        const float* __restrict__ tscale,
                        const int* __restrict__ pairs,
                        float* __restrict__ G) {
  __shared__ float Gs[DD][DD];
  const int t = threadIdx.x;  // 64 threads
  for (int c = 0; c < DD; ++c) Gs[t][c] = (t == c) ? 1.0f : 0.0f;
  const float ts = tscale[0];
  for (int r = 0; r < ROT; ++r) {
    const int i = pairs[2 * r], j = pairs[2 * r + 1];
    const float th = thetas[r] * ts;
    const float cc = cosf(th), sn = sinf(th);
    if (i == j) {
      Gs[t][i] *= sn;
    } else {
      const float a = Gs[t][i], b = Gs[t][j];
      Gs[t][i] = a * cc + b * sn;
      Gs[t][j] = b * cc - a * sn;
    }
  }
  for (int c = 0; c < DD; ++c) G[t * DD + c] = Gs[t][c];
}

// M = G @ matrix, one thread per element (16 blocks x 256).
__global__ void setup_Mk(const float* __restrict__ G,
                         const float* __restrict__ matrix,
                         float* __restrict__ M) {
  const int e = blockIdx.x * 256 + threadIdx.x;
  const int row = e >> 6, col = e & 63;
  float a0 = 0.f, a1 = 0.f, a2 = 0.f, a3 = 0.f;
  for (int k = 0; k < DD; k += 4) {
    a0 = fmaf(G[row * DD + k], matrix[k * DD + col], a0);
    a1 = fmaf(G[row * DD + k + 1], matrix[(k + 1) * DD + col], a1);
    a2 = fmaf(G[row * DD + k + 2], matrix[(k + 2) * DD + col], a2);
    a3 = fmaf(G[row * DD + k + 3], matrix[(k + 3) * DD + col], a3);
  }
  M[e] = (a0 + a1) + (a2 + a3);
}

// cos/sin table PRESCALED by 32 (the sqrt(dims) factor fused here).
// tab[s*64 + d] = 32*cos(s*invf[d]); tab[s*64 + 32 + d] = 32*sin(...)
__global__ void setup_table(const float* __restrict__ invf,
                            float* __restrict__ tab) {
  const int idx = blockIdx.x * 256 + threadIdx.x;
  if (idx >= SS * 32) return;
  const int s = idx >> 5, d = idx & 31;
  const float ang = (float)s * invf[d];
  tab[s * 64 + d] = 32.0f * cosf(ang);
  tab[s * 64 + 32 + d] = 32.0f * sinf(ang);
}

// ---------------------------------------------------------------------------
// Main kernel: coalesced load -> LDS -> per-thread 32-col matvec (M scalar-
// loaded) -> RoPE epilogue -> LDS -> coalesced store.
// ---------------------------------------------------------------------------
__global__ __launch_bounds__(256) void apply_rot(
    const float* __restrict__ x, const float* __restrict__ M,
    const float* __restrict__ tab, const float* __restrict__ invf,
    float* __restrict__ out) {
  __shared__ float lds[RPB * LSTR];  // 33280 B -> 4 blocks/CU
  const int tid = threadIdx.x;
  const size_t R0 = (size_t)blockIdx.x * RPB;

  // Phase 1: coalesced float4 loads of 128 rows -> padded LDS tile.
  const float4* __restrict__ xg = (const float4*)x + R0 * 16;
#pragma unroll
  for (int i = 0; i < 8; ++i) {
    const int f = i * 256 + tid;  // float4 index in tile [0,2048)
    const int row = f >> 4, c4 = f & 15;
    const float4 v = xg[f];
    *(float4*)&lds[row * LSTR + c4 * 4] = v;
  }
  __syncthreads();

  // Phase 2: thread (r,h) computes cols [32h, 32h+32) of row r.
  const int r = tid & (RPB - 1);
  const int h = __builtin_amdgcn_readfirstlane(tid >> 7);  // wave-uniform
  const float* __restrict__ Mh = M + h * 32;
  const float* __restrict__ xr = &lds[r * LSTR];

  float acc[32];
#pragma unroll
  for (int c = 0; c < 32; ++c) acc[c] = 0.0f;

  for (int k4 = 0; k4 < 16; ++k4) {
    const float4 xv = *(const float4*)&xr[k4 * 4];
    const float* __restrict__ m0 = Mh + k4 * 4 * DD;  // uniform -> s_load
#pragma unroll
    for (int c = 0; c < 32; ++c) acc[c] = fmaf(xv.x, m0[c], acc[c]);
#pragma unroll
    for (int c = 0; c < 32; ++c) acc[c] = fmaf(xv.y, m0[DD + c], acc[c]);
#pragma unroll
    for (int c = 0; c < 32; ++c) acc[c] = fmaf(xv.z, m0[2 * DD + c], acc[c]);
#pragma unroll
    for (int c = 0; c < 32; ++c) acc[c] = fmaf(xv.w, m0[3 * DD + c], acc[c]);
  }

  // Epilogue: RoPE pairs (2d,2d+1) -> out cols d (lo) and 32+d (hi), d=16h+d'.
  const int g = (int)R0 + r;
  const int spos = (g >> 4) & (SS - 1);
  float cz[16], sz[16];
  if (tab) {
    const float4* __restrict__ tc = (const float4*)(tab + spos * 64 + h * 16);
    const float4* __restrict__ tn =
        (const float4*)(tab + spos * 64 + 32 + h * 16);
#pragma unroll
    for (int q = 0; q < 4; ++q) {
      *(float4*)&cz[4 * q] = tc[q];
      *(float4*)&sz[4 * q] = tn[q];
    }
  } else {
#pragma unroll
    for (int d = 0; d < 16; ++d) {
      const float ang = (float)spos * invf[h * 16 + d];
      cz[d] = 32.0f * cosf(ang);
      sz[d] = 32.0f * sinf(ang);
    }
  }

  float lo[16], hi[16];
#pragma unroll
  for (int d = 0; d < 16; ++d) {
    const float e = acc[2 * d], o = acc[2 * d + 1];
    lo[d] = e * cz[d] - o * sz[d];
    hi[d] = e * sz[d] + o * cz[d];
  }

  __syncthreads();  // all LDS x-reads complete before overwrite
  float* __restrict__ orow = &lds[r * LSTR];
#pragma unroll
  for (int q = 0; q < 4; ++q) {
    *(float4*)&orow[16 * h + 4 * q] = *(float4*)&lo[4 * q];
    *(float4*)&orow[32 + 16 * h + 4 * q] = *(float4*)&hi[4 * q];
  }
  __syncthreads();

  // Phase 3: coalesced float4 stores from LDS.
  float4* __restrict__ og = (float4*)out + R0 * 16;
#pragma unroll
  for (int i = 0; i < 8; ++i) {
    const int f = i * 256 + tid;
    const int row = f >> 4, c4 = f & 15;
    og[f] = *(float4*)&lds[row * LSTR + c4 * 4];
  }
}

// ---------------------------------------------------------------------------
extern "C" void kernel_launch(void* const* d_in, const int* in_sizes, int n_in,
                              void* d_out, int out_size, void* d_ws,
                              size_t ws_size, hipStream_t stream) {
  const float* x = (const float*)d_in[0];       // (4, 8192, 1024) f32
  const float* matrix = (const float*)d_in[1];  // (64, 64) f32
  const float* thetas = (const float*)d_in[2];  // (32,) f32
  const float* tscale = (const float*)d_in[3];  // (1,) f32
  const float* invf = (const float*)d_in[4];    // (32,) f32
  const int* pairs = (const int*)d_in[5];       // (32, 2) i32
  float* out = (float*)d_out;

  float* G = (float*)d_ws;      // 4096 f
  float* M = G + DD * DD;       // 4096 f
  float* tab = M + DD * DD;     // SS*64 f = 2 MB
  const size_t need = (size_t)(2 * DD * DD + SS * 64) * sizeof(float);
  const bool have_tab = ws_size >= need;

  setup_G<<<1, 64, 0, stream>>>(thetas, tscale, pairs, G);
  setup_Mk<<<16, 256, 0, stream>>>(G, matrix, M);
  if (have_tab) setup_table<<<(SS * 32) / 256, 256, 0, stream>>>(invf, tab);
  apply_rot<<<NG / RPB, 256, 0, stream>>>(x, M, have_tab ? tab : nullptr, invf,
                                          out);
}